// Round 5
// baseline (384.451 us; speedup 1.0000x reference)
//
#include <hip/hip_runtime.h>
#include <cmath>

// RestorationLoss = (1 - mean(SSIM(r_low, r_high))) + mean((r_low - r_high)^2)
// Separable 11x11 gaussian; 4 conv fields: mu1, mu2, S=conv(a^2+b^2), P=conv(ab).
// out = 1 + sum(d^2 - ssim_px)/N.
// R5: 256-thr blocks (the shape that ran in R2), occupancy via smaller tile:
// TILE_H=16 -> 26.6KB LDS -> 6 blocks/CU = 24 waves/CU. float4-packed hbuf
// (b128 phase-2 reads), row-OOB via clamped-row load + output mask,
// per-thread col edge path.

#define HH 512
#define WW 512
#define TILE_H 16
#define TILE_W 64
#define HB (TILE_H + 10)                          // 26 staged rows
#define NPLANES 48
#define CT (WW / TILE_W)                          // 8
#define RT (HH / TILE_H)                          // 32
#define NBLOCKS (NPLANES * RT * CT)               // 12288

struct GW { float g[11]; };

__global__ __launch_bounds__(256, 6)              // 6 blocks/CU -> 24 waves/CU, VGPR<=85
void ssim_main(const float* __restrict__ img1, const float* __restrict__ img2,
               float* __restrict__ partial, GW gw)
{
    __shared__ float4 hbuf[HB][TILE_W];           // (mu1,mu2,S,P) packed: 26624 B
    __shared__ float red[4];

    const int tid   = threadIdx.x;
    const int bx    = blockIdx.x;
    const int by    = blockIdx.y;
    const int plane = blockIdx.z;
    const int row0  = by * TILE_H;
    const int col0  = bx * TILE_W;
    const float* p1 = img1 + (size_t)plane * (HH * WW);
    const float* p2 = img2 + (size_t)plane * (HH * WW);

    // ---- Phase 1: horizontal conv (global -> regs -> LDS) ----
    {
        const int  cg    = tid & 15;              // col group: tile cols 4cg..4cg+3
        const int  rs    = tid >> 4;              // 0..15
        const int  cbase = col0 + 4 * cg - 8;     // 20-float window start, 16B aligned
        const bool colok = (cbase >= 0) && (cbase + 20 <= WW);

        for (int rl = rs; rl < HB; rl += 16) {    // trip 2 for rs<10, else 1
            const int   grow  = row0 - 5 + rl;
            const int   growc = min(max(grow, 0), HH - 1);       // always in-bounds
            const float rmask = (grow >= 0 && grow < HH) ? 1.f : 0.f;
            const float* r1   = p1 + (size_t)growc * WW;
            const float* r2   = p2 + (size_t)growc * WW;

            float x1[20], x2[20];
            if (colok) {
                const float4* q1 = reinterpret_cast<const float4*>(r1 + cbase);
                const float4* q2 = reinterpret_cast<const float4*>(r2 + cbase);
                #pragma unroll
                for (int v = 0; v < 5; ++v) {
                    float4 a = q1[v], b = q2[v];
                    x1[4*v+0] = a.x; x1[4*v+1] = a.y; x1[4*v+2] = a.z; x1[4*v+3] = a.w;
                    x2[4*v+0] = b.x; x2[4*v+1] = b.y; x2[4*v+2] = b.z; x2[4*v+3] = b.w;
                }
            } else {
                // col-edge threads only (2 of 16 cg in edge-col blocks)
                #pragma unroll
                for (int e = 0; e < 20; ++e) {
                    int   gc  = cbase + e;
                    int   gcc = min(max(gc, 0), WW - 1);
                    float m   = (gc >= 0 && gc < WW) ? 1.f : 0.f;
                    x1[e] = r1[gcc] * m;
                    x2[e] = r2[gcc] * m;
                }
            }

            float acc[4][4];
            #pragma unroll
            for (int k = 0; k < 4; ++k)
                #pragma unroll
                for (int i = 0; i < 4; ++i) acc[k][i] = 0.f;
            // out col i uses element e = i + j + 3 (j = tap 0..10)
            #pragma unroll
            for (int e = 3; e <= 16; ++e) {
                float a  = x1[e], b = x2[e];
                float v2 = a * a + b * b;
                float v3 = a * b;
                #pragma unroll
                for (int i = 0; i < 4; ++i) {
                    int j = e - 3 - i;
                    if (j >= 0 && j < 11) {
                        float w = gw.g[j];
                        acc[0][i] += w * a;
                        acc[1][i] += w * b;
                        acc[2][i] += w * v2;
                        acc[3][i] += w * v3;
                    }
                }
            }
            // row-OOB rows contribute zero: mask conv outputs (equivalent to
            // zero-padded inputs since all 4 fields vanish when a=b=0)
            #pragma unroll
            for (int i = 0; i < 4; ++i)
                hbuf[rl][4 * cg + i] =
                    make_float4(acc[0][i] * rmask, acc[1][i] * rmask,
                                acc[2][i] * rmask, acc[3][i] * rmask);
        }
    }
    __syncthreads();

    // ---- Phase 2: vertical conv + ssim + mse (4 rows/thread) ----
    float local = 0.f;
    {
        const int tx = tid & 63;                  // column
        const int rg = tid >> 6;                  // 0..3 -> rows 4rg..4rg+3
        float4 res[4];
        #pragma unroll
        for (int p = 0; p < 4; ++p) res[p] = make_float4(0.f, 0.f, 0.f, 0.f);
        #pragma unroll
        for (int j = 0; j < 14; ++j) {            // window rows rg*4 .. rg*4+13
            float4 w4 = hbuf[rg * 4 + j][tx];
            #pragma unroll
            for (int p = 0; p < 4; ++p) {
                int t = j - p;
                if (t >= 0 && t < 11) {
                    float w = gw.g[t];
                    res[p].x += w * w4.x;
                    res[p].y += w * w4.y;
                    res[p].z += w * w4.z;
                    res[p].w += w * w4.w;
                }
            }
        }
        const float C1c = 0.0001f, C2c = 0.0009f;
        #pragma unroll
        for (int p = 0; p < 4; ++p) {
            int   r   = rg * 4 + p;
            float mu1 = res[p].x, mu2 = res[p].y;
            float S   = res[p].z, P   = res[p].w;
            float m11 = mu1 * mu1, m22 = mu2 * mu2, m12 = mu1 * mu2;
            float num = (2.f * m12 + C1c) * (2.f * (P - m12) + C2c);
            float den = (m11 + m22 + C1c) * ((S - m11 - m22) + C2c);
            float ssim = num / den;
            size_t off = (size_t)(row0 + r) * WW + col0 + tx;
            float a = p1[off], b = p2[off];
            float d = a - b;
            local += d * d - ssim;
        }
    }

    // ---- block reduce ----
    #pragma unroll
    for (int off = 32; off > 0; off >>= 1) local += __shfl_down(local, off);
    if ((tid & 63) == 0) red[tid >> 6] = local;
    __syncthreads();
    if (tid == 0) {
        int bid = (plane * RT + by) * CT + bx;
        partial[bid] = (red[0] + red[1]) + (red[2] + red[3]);
    }
}

__global__ __launch_bounds__(256)
void ssim_finish(const float* __restrict__ partial, float* __restrict__ out)
{
    __shared__ float red[256];
    float s = 0.f;
    for (int i = threadIdx.x; i < NBLOCKS; i += 256) s += partial[i];
    red[threadIdx.x] = s;
    __syncthreads();
    for (int step = 128; step > 0; step >>= 1) {
        if ((int)threadIdx.x < step) red[threadIdx.x] += red[threadIdx.x + step];
        __syncthreads();
    }
    if (threadIdx.x == 0)
        out[0] = 1.0f + red[0] * (1.0f / 12582912.0f);
}

extern "C" void kernel_launch(void* const* d_in, const int* in_sizes, int n_in,
                              void* d_out, int out_size, void* d_ws, size_t ws_size,
                              hipStream_t stream)
{
    const float* r_low  = (const float*)d_in[0];
    const float* r_high = (const float*)d_in[1];
    float* out     = (float*)d_out;
    float* partial = (float*)d_ws;                       // 12288 floats = 48 KB

    GW gw;                                               // gaussian -> SGPRs
    {
        float s = 0.f;
        for (int i = 0; i < 11; ++i) {
            float c = (float)(i - 5);
            gw.g[i] = expf(-(c * c) / 4.5f);             // 2*sigma^2 = 4.5
            s += gw.g[i];
        }
        for (int i = 0; i < 11; ++i) gw.g[i] /= s;
    }

    dim3 grid(CT, RT, NPLANES);
    ssim_main<<<grid, dim3(256), 0, stream>>>(r_low, r_high, partial, gw);
    ssim_finish<<<1, dim3(256), 0, stream>>>(partial, out);
}

// Round 7
// 269.029 us; speedup vs baseline: 1.4290x; 1.4290x over previous
//
#include <hip/hip_runtime.h>
#include <cmath>

// RestorationLoss = (1 - mean(SSIM(r_low, r_high))) + mean((r_low - r_high)^2)
// Separable 11x11 gaussian; 4 conv fields: mu1, mu2, S=conv(a^2+b^2), P=conv(ab).
// out = 1 + sum(d^2 - ssim_px)/N.
// R7 (= R6 resubmitted; R6 bench was an infra failure — R1/R2 proved identical
// source can fail then pass): R2's proven ingredients (256 thr, PLANAR hbuf ->
// 0 bank conflicts, loose launch_bounds -> no spills) + occupancy via
// TILE_H=16: 26.6KB LDS -> 6 blocks/CU = 24 waves/CU (R2 had 12).
// R5 lesson: launch_bounds(256,6) VGPR cap 85 caused spill cascade (VGPR 40,
// 528MB scratch writes); interleaved float4 hbuf caused 7.7M bank conflicts.

#define HH 512
#define WW 512
#define TILE_H 16
#define TILE_W 64
#define HB (TILE_H + 10)                          // 26 staged rows
#define NPLANES 48
#define CT (WW / TILE_W)                          // 8
#define RT (HH / TILE_H)                          // 32
#define NBLOCKS (NPLANES * RT * CT)               // 12288

struct GW { float g[11]; };

__global__ __launch_bounds__(256, 4)              // VGPR cap 128: no spill risk
void ssim_main(const float* __restrict__ img1, const float* __restrict__ img2,
               float* __restrict__ partial, GW gw)
{
    __shared__ float hbuf[4][HB][TILE_W];         // planar: 26624 B -> 6 blocks/CU
    __shared__ float red[4];

    const int tid   = threadIdx.x;
    const int bx    = blockIdx.x;
    const int by    = blockIdx.y;
    const int plane = blockIdx.z;
    const int row0  = by * TILE_H;
    const int col0  = bx * TILE_W;
    const float* p1 = img1 + (size_t)plane * (HH * WW);
    const float* p2 = img2 + (size_t)plane * (HH * WW);

    // ---- Phase 1: horizontal conv (global -> regs -> LDS) ----
    {
        const int  cg    = tid & 15;              // col group: tile cols 4cg..4cg+3
        const int  rs    = tid >> 4;              // 0..15
        const int  cbase = col0 + 4 * cg - 8;     // 20-float window, 16B aligned
        const bool colok = (cbase >= 0) && (cbase + 20 <= WW);

        for (int rl = rs; rl < HB; rl += 16) {    // trip 2 for rs<10, else 1
            const int   grow  = row0 - 5 + rl;
            const int   growc = min(max(grow, 0), HH - 1);       // always in-bounds
            const float rmask = (grow >= 0 && grow < HH) ? 1.f : 0.f;
            const float* r1   = p1 + (size_t)growc * WW;
            const float* r2   = p2 + (size_t)growc * WW;

            float x1[20], x2[20];
            if (colok) {
                const float4* q1 = reinterpret_cast<const float4*>(r1 + cbase);
                const float4* q2 = reinterpret_cast<const float4*>(r2 + cbase);
                #pragma unroll
                for (int v = 0; v < 5; ++v) {
                    float4 a = q1[v], b = q2[v];
                    x1[4*v+0] = a.x; x1[4*v+1] = a.y; x1[4*v+2] = a.z; x1[4*v+3] = a.w;
                    x2[4*v+0] = b.x; x2[4*v+1] = b.y; x2[4*v+2] = b.z; x2[4*v+3] = b.w;
                }
            } else {
                // col-edge threads only (2 of 16 cg in edge-col blocks)
                #pragma unroll
                for (int e = 0; e < 20; ++e) {
                    int   gc  = cbase + e;
                    int   gcc = min(max(gc, 0), WW - 1);
                    float m   = (gc >= 0 && gc < WW) ? 1.f : 0.f;
                    x1[e] = r1[gcc] * m;
                    x2[e] = r2[gcc] * m;
                }
            }

            float acc[4][4];
            #pragma unroll
            for (int k = 0; k < 4; ++k)
                #pragma unroll
                for (int i = 0; i < 4; ++i) acc[k][i] = 0.f;
            // out col i uses element e = i + j + 3 (j = tap 0..10)
            #pragma unroll
            for (int e = 3; e <= 16; ++e) {
                float a  = x1[e], b = x2[e];
                float v2 = a * a + b * b;
                float v3 = a * b;
                #pragma unroll
                for (int i = 0; i < 4; ++i) {
                    int j = e - 3 - i;
                    if (j >= 0 && j < 11) {
                        float w = gw.g[j];
                        acc[0][i] += w * a;
                        acc[1][i] += w * b;
                        acc[2][i] += w * v2;
                        acc[3][i] += w * v3;
                    }
                }
            }
            // row-OOB rows contribute zero: mask conv outputs (equivalent to
            // zero-padded inputs since all 4 fields vanish when a=b=0)
            #pragma unroll
            for (int k = 0; k < 4; ++k)
                *reinterpret_cast<float4*>(&hbuf[k][rl][4 * cg]) =
                    make_float4(acc[k][0] * rmask, acc[k][1] * rmask,
                                acc[k][2] * rmask, acc[k][3] * rmask);
        }
    }
    __syncthreads();

    // ---- Phase 2: vertical conv + ssim + mse (4 rows/thread) ----
    float local = 0.f;
    {
        const int tx = tid & 63;                  // column
        const int rg = tid >> 6;                  // 0..3 -> rows 4rg..4rg+3
        float res[4][4];                          // [field][row]
        #pragma unroll
        for (int k = 0; k < 4; ++k) {
            float win[14];
            #pragma unroll
            for (int t = 0; t < 14; ++t) win[t] = hbuf[k][rg * 4 + t][tx];
            #pragma unroll
            for (int p = 0; p < 4; ++p) {
                float s = 0.f;
                #pragma unroll
                for (int j = 0; j < 11; ++j) s += gw.g[j] * win[p + j];
                res[k][p] = s;
            }
        }
        const float C1c = 0.0001f, C2c = 0.0009f;
        #pragma unroll
        for (int p = 0; p < 4; ++p) {
            int   r   = rg * 4 + p;
            float mu1 = res[0][p], mu2 = res[1][p];
            float S   = res[2][p], P   = res[3][p];
            float m11 = mu1 * mu1, m22 = mu2 * mu2, m12 = mu1 * mu2;
            float num = (2.f * m12 + C1c) * (2.f * (P - m12) + C2c);
            float den = (m11 + m22 + C1c) * ((S - m11 - m22) + C2c);
            float ssim = num / den;
            size_t off = (size_t)(row0 + r) * WW + col0 + tx;
            float a = p1[off], b = p2[off];
            float d = a - b;
            local += d * d - ssim;
        }
    }

    // ---- block reduce ----
    #pragma unroll
    for (int off = 32; off > 0; off >>= 1) local += __shfl_down(local, off);
    if ((tid & 63) == 0) red[tid >> 6] = local;
    __syncthreads();
    if (tid == 0) {
        int bid = (plane * RT + by) * CT + bx;
        partial[bid] = (red[0] + red[1]) + (red[2] + red[3]);
    }
}

__global__ __launch_bounds__(256)
void ssim_finish(const float* __restrict__ partial, float* __restrict__ out)
{
    __shared__ float red[256];
    float s = 0.f;
    for (int i = threadIdx.x; i < NBLOCKS; i += 256) s += partial[i];
    red[threadIdx.x] = s;
    __syncthreads();
    for (int step = 128; step > 0; step >>= 1) {
        if ((int)threadIdx.x < step) red[threadIdx.x] += red[threadIdx.x + step];
        __syncthreads();
    }
    if (threadIdx.x == 0)
        out[0] = 1.0f + red[0] * (1.0f / 12582912.0f);
}

extern "C" void kernel_launch(void* const* d_in, const int* in_sizes, int n_in,
                              void* d_out, int out_size, void* d_ws, size_t ws_size,
                              hipStream_t stream)
{
    const float* r_low  = (const float*)d_in[0];
    const float* r_high = (const float*)d_in[1];
    float* out     = (float*)d_out;
    float* partial = (float*)d_ws;                       // 12288 floats = 48 KB

    GW gw;                                               // gaussian -> SGPRs
    {
        float s = 0.f;
        for (int i = 0; i < 11; ++i) {
            float c = (float)(i - 5);
            gw.g[i] = expf(-(c * c) / 4.5f);             // 2*sigma^2 = 4.5
            s += gw.g[i];
        }
        for (int i = 0; i < 11; ++i) gw.g[i] /= s;
    }

    dim3 grid(CT, RT, NPLANES);
    ssim_main<<<grid, dim3(256), 0, stream>>>(r_low, r_high, partial, gw);
    ssim_finish<<<1, dim3(256), 0, stream>>>(partial, out);
}

// Round 8
// 221.849 us; speedup vs baseline: 1.7329x; 1.2127x over previous
//
#include <hip/hip_runtime.h>
#include <cmath>

// RestorationLoss = (1 - mean(SSIM(r_low, r_high))) + mean((r_low - r_high)^2)
// Separable 11x11 gaussian; 4 conv fields: mu1, mu2, S=conv(a^2+b^2), P=conv(ab).
// out = 1 + sum(d^2 - ssim_px)/N.
// R8: R7 with __launch_bounds__(256,3) — the R2-proven annotation (68 VGPR,
// zero spill). R7's (256,4) made the allocator snap to the 64-VGPR occupancy
// step and spill ~11 floats/thread: WRITE_SIZE 146 MB, occupancy throttled to
// 28% by scratch, dur 174us. R5 lesson stands: hard caps near the need cause
// spill cascades. LDS (26.6KB planar -> 6 blocks/CU = 24 waves) must stay the
// binding occupancy constraint, not VGPRs, not scratch.

#define HH 512
#define WW 512
#define TILE_H 16
#define TILE_W 64
#define HB (TILE_H + 10)                          // 26 staged rows
#define NPLANES 48
#define CT (WW / TILE_W)                          // 8
#define RT (HH / TILE_H)                          // 32
#define NBLOCKS (NPLANES * RT * CT)               // 12288

struct GW { float g[11]; };

__global__ __launch_bounds__(256, 3)              // VGPR cap ~170: allocator free
void ssim_main(const float* __restrict__ img1, const float* __restrict__ img2,
               float* __restrict__ partial, GW gw)
{
    __shared__ float hbuf[4][HB][TILE_W];         // planar: 26624 B -> 6 blocks/CU
    __shared__ float red[4];

    const int tid   = threadIdx.x;
    const int bx    = blockIdx.x;
    const int by    = blockIdx.y;
    const int plane = blockIdx.z;
    const int row0  = by * TILE_H;
    const int col0  = bx * TILE_W;
    const float* p1 = img1 + (size_t)plane * (HH * WW);
    const float* p2 = img2 + (size_t)plane * (HH * WW);

    // ---- Phase 1: horizontal conv (global -> regs -> LDS) ----
    {
        const int  cg    = tid & 15;              // col group: tile cols 4cg..4cg+3
        const int  rs    = tid >> 4;              // 0..15
        const int  cbase = col0 + 4 * cg - 8;     // 20-float window, 16B aligned
        const bool colok = (cbase >= 0) && (cbase + 20 <= WW);

        for (int rl = rs; rl < HB; rl += 16) {    // trip 2 for rs<10, else 1
            const int   grow  = row0 - 5 + rl;
            const int   growc = min(max(grow, 0), HH - 1);       // always in-bounds
            const float rmask = (grow >= 0 && grow < HH) ? 1.f : 0.f;
            const float* r1   = p1 + (size_t)growc * WW;
            const float* r2   = p2 + (size_t)growc * WW;

            float x1[20], x2[20];
            if (colok) {
                const float4* q1 = reinterpret_cast<const float4*>(r1 + cbase);
                const float4* q2 = reinterpret_cast<const float4*>(r2 + cbase);
                #pragma unroll
                for (int v = 0; v < 5; ++v) {
                    float4 a = q1[v], b = q2[v];
                    x1[4*v+0] = a.x; x1[4*v+1] = a.y; x1[4*v+2] = a.z; x1[4*v+3] = a.w;
                    x2[4*v+0] = b.x; x2[4*v+1] = b.y; x2[4*v+2] = b.z; x2[4*v+3] = b.w;
                }
            } else {
                // col-edge threads only (2 of 16 cg in edge-col blocks)
                #pragma unroll
                for (int e = 0; e < 20; ++e) {
                    int   gc  = cbase + e;
                    int   gcc = min(max(gc, 0), WW - 1);
                    float m   = (gc >= 0 && gc < WW) ? 1.f : 0.f;
                    x1[e] = r1[gcc] * m;
                    x2[e] = r2[gcc] * m;
                }
            }

            float acc[4][4];
            #pragma unroll
            for (int k = 0; k < 4; ++k)
                #pragma unroll
                for (int i = 0; i < 4; ++i) acc[k][i] = 0.f;
            // out col i uses element e = i + j + 3 (j = tap 0..10)
            #pragma unroll
            for (int e = 3; e <= 16; ++e) {
                float a  = x1[e], b = x2[e];
                float v2 = a * a + b * b;
                float v3 = a * b;
                #pragma unroll
                for (int i = 0; i < 4; ++i) {
                    int j = e - 3 - i;
                    if (j >= 0 && j < 11) {
                        float w = gw.g[j];
                        acc[0][i] += w * a;
                        acc[1][i] += w * b;
                        acc[2][i] += w * v2;
                        acc[3][i] += w * v3;
                    }
                }
            }
            // row-OOB rows contribute zero: mask conv outputs (equivalent to
            // zero-padded inputs since all 4 fields vanish when a=b=0)
            #pragma unroll
            for (int k = 0; k < 4; ++k)
                *reinterpret_cast<float4*>(&hbuf[k][rl][4 * cg]) =
                    make_float4(acc[k][0] * rmask, acc[k][1] * rmask,
                                acc[k][2] * rmask, acc[k][3] * rmask);
        }
    }
    __syncthreads();

    // ---- Phase 2: vertical conv + ssim + mse (4 rows/thread) ----
    float local = 0.f;
    {
        const int tx = tid & 63;                  // column
        const int rg = tid >> 6;                  // 0..3 -> rows 4rg..4rg+3
        float res[4][4];                          // [field][row]
        #pragma unroll
        for (int k = 0; k < 4; ++k) {
            float win[14];
            #pragma unroll
            for (int t = 0; t < 14; ++t) win[t] = hbuf[k][rg * 4 + t][tx];
            #pragma unroll
            for (int p = 0; p < 4; ++p) {
                float s = 0.f;
                #pragma unroll
                for (int j = 0; j < 11; ++j) s += gw.g[j] * win[p + j];
                res[k][p] = s;
            }
        }
        const float C1c = 0.0001f, C2c = 0.0009f;
        #pragma unroll
        for (int p = 0; p < 4; ++p) {
            int   r   = rg * 4 + p;
            float mu1 = res[0][p], mu2 = res[1][p];
            float S   = res[2][p], P   = res[3][p];
            float m11 = mu1 * mu1, m22 = mu2 * mu2, m12 = mu1 * mu2;
            float num = (2.f * m12 + C1c) * (2.f * (P - m12) + C2c);
            float den = (m11 + m22 + C1c) * ((S - m11 - m22) + C2c);
            float ssim = num / den;
            size_t off = (size_t)(row0 + r) * WW + col0 + tx;
            float a = p1[off], b = p2[off];
            float d = a - b;
            local += d * d - ssim;
        }
    }

    // ---- block reduce ----
    #pragma unroll
    for (int off = 32; off > 0; off >>= 1) local += __shfl_down(local, off);
    if ((tid & 63) == 0) red[tid >> 6] = local;
    __syncthreads();
    if (tid == 0) {
        int bid = (plane * RT + by) * CT + bx;
        partial[bid] = (red[0] + red[1]) + (red[2] + red[3]);
    }
}

__global__ __launch_bounds__(256)
void ssim_finish(const float* __restrict__ partial, float* __restrict__ out)
{
    __shared__ float red[256];
    float s = 0.f;
    for (int i = threadIdx.x; i < NBLOCKS; i += 256) s += partial[i];
    red[threadIdx.x] = s;
    __syncthreads();
    for (int step = 128; step > 0; step >>= 1) {
        if ((int)threadIdx.x < step) red[threadIdx.x] += red[threadIdx.x + step];
        __syncthreads();
    }
    if (threadIdx.x == 0)
        out[0] = 1.0f + red[0] * (1.0f / 12582912.0f);
}

extern "C" void kernel_launch(void* const* d_in, const int* in_sizes, int n_in,
                              void* d_out, int out_size, void* d_ws, size_t ws_size,
                              hipStream_t stream)
{
    const float* r_low  = (const float*)d_in[0];
    const float* r_high = (const float*)d_in[1];
    float* out     = (float*)d_out;
    float* partial = (float*)d_ws;                       // 12288 floats = 48 KB

    GW gw;                                               // gaussian -> SGPRs
    {
        float s = 0.f;
        for (int i = 0; i < 11; ++i) {
            float c = (float)(i - 5);
            gw.g[i] = expf(-(c * c) / 4.5f);             // 2*sigma^2 = 4.5
            s += gw.g[i];
        }
        for (int i = 0; i < 11; ++i) gw.g[i] /= s;
    }

    dim3 grid(CT, RT, NPLANES);
    ssim_main<<<grid, dim3(256), 0, stream>>>(r_low, r_high, partial, gw);
    ssim_finish<<<1, dim3(256), 0, stream>>>(partial, out);
}

// Round 9
// 207.745 us; speedup vs baseline: 1.8506x; 1.0679x over previous
//
#include <hip/hip_runtime.h>
#include <cmath>

// RestorationLoss = (1 - mean(SSIM(r_low, r_high))) + mean((r_low - r_high)^2)
// Separable 11x11 gaussian; 4 conv fields: mu1, mu2, S=conv(a^2+b^2), P=conv(ab).
// out = 1 + sum(d^2 - ssim_px)/N.
// R9: R8 + manual software pipeline of phase 1. R8 counters: VALUBusy 51%,
// occupancy 23% (7.4 waves/CU) despite 24 static — per-wave ILP is the limit,
// not residency: the dynamic rl-loop (trip 1..2) blocked load/conv overlap.
// Now: issue loads for BOTH staged rows (20x float4) up front, conv row A
// under row B's latency, conv row B guarded by rs<10. MSE pixel loads hoisted
// pre-barrier. Config frozen: 256 thr, launch_bounds(256,3) (R5/R7 lesson:
// tight caps => spill cascade; R8 proved (256,3) lands at natural VGPR need),
// planar hbuf 26.6KB (0 conflicts), TILE_H=16.

#define HH 512
#define WW 512
#define TILE_H 16
#define TILE_W 64
#define HB (TILE_H + 10)                          // 26 staged rows
#define NPLANES 48
#define CT (WW / TILE_W)                          // 8
#define RT (HH / TILE_H)                          // 32
#define NBLOCKS (NPLANES * RT * CT)               // 12288

struct GW { float g[11]; };

__global__ __launch_bounds__(256, 3)              // VGPR cap ~170: allocator free
void ssim_main(const float* __restrict__ img1, const float* __restrict__ img2,
               float* __restrict__ partial, GW gw)
{
    __shared__ float hbuf[4][HB][TILE_W];         // planar: 26624 B
    __shared__ float red[4];

    const int tid   = threadIdx.x;
    const int bx    = blockIdx.x;
    const int by    = blockIdx.y;
    const int plane = blockIdx.z;
    const int row0  = by * TILE_H;
    const int col0  = bx * TILE_W;
    const float* p1 = img1 + (size_t)plane * (HH * WW);
    const float* p2 = img2 + (size_t)plane * (HH * WW);

    const int  cg    = tid & 15;                  // col group: tile cols 4cg..4cg+3
    const int  rs    = tid >> 4;                  // 0..15
    const int  cbase = col0 + 4 * cg - 8;         // 20-float window, 16B aligned
    const bool colok = (cbase >= 0) && (cbase + 20 <= WW);

    // load one staged row's 20-float windows for both images into registers
    auto loadRow = [&](int rl, float* x1, float* x2) {
        const int grow  = row0 - 5 + rl;
        const int growc = min(max(grow, 0), HH - 1);      // always in-bounds
        const float* r1 = p1 + (size_t)growc * WW;
        const float* r2 = p2 + (size_t)growc * WW;
        if (colok) {
            const float4* q1 = reinterpret_cast<const float4*>(r1 + cbase);
            const float4* q2 = reinterpret_cast<const float4*>(r2 + cbase);
            #pragma unroll
            for (int v = 0; v < 5; ++v) {
                float4 a = q1[v], b = q2[v];
                x1[4*v+0] = a.x; x1[4*v+1] = a.y; x1[4*v+2] = a.z; x1[4*v+3] = a.w;
                x2[4*v+0] = b.x; x2[4*v+1] = b.y; x2[4*v+2] = b.z; x2[4*v+3] = b.w;
            }
        } else {                                  // col-edge threads only
            #pragma unroll
            for (int e = 0; e < 20; ++e) {
                int   gc  = cbase + e;
                int   gcc = min(max(gc, 0), WW - 1);
                float m   = (gc >= 0 && gc < WW) ? 1.f : 0.f;
                x1[e] = r1[gcc] * m;
                x2[e] = r2[gcc] * m;
            }
        }
    };

    // horizontal conv of one staged row -> hbuf[.][rl]
    auto convStore = [&](int rl, const float* x1, const float* x2) {
        const int   grow  = row0 - 5 + rl;
        const float rmask = (grow >= 0 && grow < HH) ? 1.f : 0.f;
        float acc[4][4];
        #pragma unroll
        for (int k = 0; k < 4; ++k)
            #pragma unroll
            for (int i = 0; i < 4; ++i) acc[k][i] = 0.f;
        #pragma unroll
        for (int e = 3; e <= 16; ++e) {           // out col i uses e = i+j+3
            float a  = x1[e], b = x2[e];
            float v2 = a * a + b * b;
            float v3 = a * b;
            #pragma unroll
            for (int i = 0; i < 4; ++i) {
                int j = e - 3 - i;
                if (j >= 0 && j < 11) {
                    float w = gw.g[j];
                    acc[0][i] += w * a;
                    acc[1][i] += w * b;
                    acc[2][i] += w * v2;
                    acc[3][i] += w * v3;
                }
            }
        }
        // row-OOB rows contribute zero (all 4 fields vanish on zero inputs)
        #pragma unroll
        for (int k = 0; k < 4; ++k)
            *reinterpret_cast<float4*>(&hbuf[k][rl][4 * cg]) =
                make_float4(acc[k][0] * rmask, acc[k][1] * rmask,
                            acc[k][2] * rmask, acc[k][3] * rmask);
    };

    // ---- Phase 1: software-pipelined (loads A+B in flight, then conv A, conv B)
    {
        float xA1[20], xA2[20], xB1[20], xB2[20];
        loadRow(rs, xA1, xA2);                    // rows 0..15
        loadRow(rs + 16, xB1, xB2);               // rows 16..31 (clamped, safe;
                                                  // issued early for pipelining)
        convStore(rs, xA1, xA2);                  // runs under B's load latency
        if (rs < 10)                              // only rows 16..25 are staged
            convStore(rs + 16, xB1, xB2);
    }

    // ---- MSE pixel prefetch (independent of LDS; consumed after barrier) ----
    const int tx = tid & 63;                      // column
    const int rg = tid >> 6;                      // 0..3 -> rows 4rg..4rg+3
    float mse_a[4], mse_b[4];
    #pragma unroll
    for (int p = 0; p < 4; ++p) {
        size_t off = (size_t)(row0 + rg * 4 + p) * WW + col0 + tx;
        mse_a[p] = p1[off];
        mse_b[p] = p2[off];
    }
    __syncthreads();

    // ---- Phase 2: vertical conv + ssim + mse (4 rows/thread) ----
    float local = 0.f;
    {
        float res[4][4];                          // [field][row]
        #pragma unroll
        for (int k = 0; k < 4; ++k) {
            float win[14];
            #pragma unroll
            for (int t = 0; t < 14; ++t) win[t] = hbuf[k][rg * 4 + t][tx];
            #pragma unroll
            for (int p = 0; p < 4; ++p) {
                float s = 0.f;
                #pragma unroll
                for (int j = 0; j < 11; ++j) s += gw.g[j] * win[p + j];
                res[k][p] = s;
            }
        }
        const float C1c = 0.0001f, C2c = 0.0009f;
        #pragma unroll
        for (int p = 0; p < 4; ++p) {
            float mu1 = res[0][p], mu2 = res[1][p];
            float S   = res[2][p], P   = res[3][p];
            float m11 = mu1 * mu1, m22 = mu2 * mu2, m12 = mu1 * mu2;
            float num = (2.f * m12 + C1c) * (2.f * (P - m12) + C2c);
            float den = (m11 + m22 + C1c) * ((S - m11 - m22) + C2c);
            float ssim = num / den;
            float d = mse_a[p] - mse_b[p];
            local += d * d - ssim;
        }
    }

    // ---- block reduce ----
    #pragma unroll
    for (int off = 32; off > 0; off >>= 1) local += __shfl_down(local, off);
    if ((tid & 63) == 0) red[tid >> 6] = local;
    __syncthreads();
    if (tid == 0) {
        int bid = (plane * RT + by) * CT + bx;
        partial[bid] = (red[0] + red[1]) + (red[2] + red[3]);
    }
}

__global__ __launch_bounds__(256)
void ssim_finish(const float* __restrict__ partial, float* __restrict__ out)
{
    __shared__ float red[256];
    float s = 0.f;
    #pragma unroll
    for (int i = 0; i < NBLOCKS / 256; ++i)       // 48 independent loads in flight
        s += partial[i * 256 + threadIdx.x];
    red[threadIdx.x] = s;
    __syncthreads();
    for (int step = 128; step > 0; step >>= 1) {
        if ((int)threadIdx.x < step) red[threadIdx.x] += red[threadIdx.x + step];
        __syncthreads();
    }
    if (threadIdx.x == 0)
        out[0] = 1.0f + red[0] * (1.0f / 12582912.0f);
}

extern "C" void kernel_launch(void* const* d_in, const int* in_sizes, int n_in,
                              void* d_out, int out_size, void* d_ws, size_t ws_size,
                              hipStream_t stream)
{
    const float* r_low  = (const float*)d_in[0];
    const float* r_high = (const float*)d_in[1];
    float* out     = (float*)d_out;
    float* partial = (float*)d_ws;                       // 12288 floats = 48 KB

    GW gw;                                               // gaussian -> SGPRs
    {
        float s = 0.f;
        for (int i = 0; i < 11; ++i) {
            float c = (float)(i - 5);
            gw.g[i] = expf(-(c * c) / 4.5f);             // 2*sigma^2 = 4.5
            s += gw.g[i];
        }
        for (int i = 0; i < 11; ++i) gw.g[i] /= s;
    }

    dim3 grid(CT, RT, NPLANES);
    ssim_main<<<grid, dim3(256), 0, stream>>>(r_low, r_high, partial, gw);
    ssim_finish<<<1, dim3(256), 0, stream>>>(partial, out);
}